// Round 6
// baseline (30656.433 us; speedup 1.0000x reference)
//
#include <hip/hip_runtime.h>
#include <hip/hip_bf16.h>

#define BATCH 64
#define SEQ   2048
#define DIN   64
#define HID   256
#define NCLS  8

__device__ __forceinline__ float sigm(float x)  { return 1.0f / (1.0f + __expf(-x)); }
__device__ __forceinline__ float tanh_f(float x){ return 1.0f - 2.0f / (__expf(2.0f * x) + 1.0f); }

// relaxed spin (no per-poll L1 invalidate), one acquire at the end
__device__ __forceinline__ void waitflag(int* f, int tgt) {
    while (__hip_atomic_load(f, __ATOMIC_RELAXED, __HIP_MEMORY_SCOPE_AGENT) < tgt) {}
    (void)__hip_atomic_load(f, __ATOMIC_ACQUIRE, __HIP_MEMORY_SCOPE_AGENT);
}

// out[b][t][c] = bfc[c]; FC overwrites t < len, so t >= len keeps exactly bfc.
__global__ void init_out_kernel(float* __restrict__ out, const float* __restrict__ bfc) {
    int idx = blockIdx.x * blockDim.x + threadIdx.x;
    if (idx < BATCH * SEQ * NCLS) out[idx] = bfc[idx & 7];
}

// ---------------------------------------------------------------------------
// Fused 2-layer LSTM, 512 blocks x 1024 thr (2 blocks/CU -> all co-resident).
//  bx<256 : L0 role. mem0=bx>>5 (8 members), q=bx&31, pair P=2*(q&15)+(q>>4)
//           (permutation puts pairs {2g,2g+1} on XCD g%8, same as l1 group g).
//           Serves batches {2P,2P+1}; 128 gate rows; w0[40]/thread.
//  bx>=256: L1 role. mem1=(bx-256)>>4 (16 members), g=(bx-256)&15.
//           Serves batches 4g..4g+3; 64 gate rows; w1[32]/thread. Consumes
//           h1[t] one step behind L0 (flagsA >= t+1) -> layers overlap and
//           hist reads are same-XCD L2 hits instead of cold HBM.
// Data moves with PLAIN loads/stores (L2-hit latency); only flags are
// agent-scope atomics (release after same-wave stores; relaxed-spin+acquire).
// 3 barriers/step; gate reduce fused into the 64 state-threads.
// ---------------------------------------------------------------------------
__global__ __launch_bounds__(1024) void lstm_fused_kernel(
    const float* __restrict__ x,
    const float* __restrict__ Wih0, const float* __restrict__ Whh0,
    const float* __restrict__ bih0, const float* __restrict__ bhh0,
    const float* __restrict__ Wih1, const float* __restrict__ Whh1,
    const float* __restrict__ bih1, const float* __restrict__ bhh1,
    const float* __restrict__ Wfc,  const float* __restrict__ bfc,
    const int* __restrict__ lengths, float* __restrict__ out,
    float* __restrict__ hist, float* __restrict__ xbuf,
    int* __restrict__ flagsA, int* __restrict__ flagsB)
{
    __shared__ __align__(16) float smem[6184];
    const int tid = threadIdx.x;

    if (blockIdx.x < 256) {
        // ------------------------------ L0 ---------------------------------
        const int mem = blockIdx.x >> 5;
        const int q   = blockIdx.x & 31;
        const int P   = 2 * (q & 15) + (q >> 4);
        const int p   = tid >> 7;            // 0..7 col-chunk (40 wide)
        const int r   = tid & 127;           // local row
        const int row = (r >> 5) * 256 + mem * 32 + (r & 31);

        float w[40];
#pragma unroll
        for (int i = 0; i < 40; ++i) {
            int col = p * 40 + i;
            w[i] = (col < DIN) ? Wih0[row * DIN + col] : Whh0[row * HID + (col - DIN)];
        }
#pragma unroll
        for (int i = 0; i < 40; ++i) asm volatile("" : "+v"(w[i]));

        float bias4[4] = {0.f, 0.f, 0.f, 0.f};
        if (tid < 64) {
            int k = tid & 31;
#pragma unroll
            for (int g4 = 0; g4 < 4; ++g4) {
                int rg = g4 * 256 + mem * 32 + k;
                bias4[g4] = bih0[rg] + bhh0[rg];
            }
        }
        float creg = 0.f;
        float xreg = 0.f;
        int   xn = 0, xj = 0;
        if (tid >= 512 && tid < 640) {
            xn = (tid - 512) >> 6; xj = tid & 63;
            xreg = x[((size_t)(2 * P + xn) * SEQ) * DIN + xj];   // t=0 prefetch
        }

        float* v  = smem;          // 640: [n][ x(64) | h1prev(256) ]
        float* pb = smem + 640;    // 2048

        for (int t = 0; t < SEQ; ++t) {
            if (t > 0 && tid < 8) waitflag(&flagsA[P * 8 + tid], t);
            __syncthreads();                                     // B1
            if (tid < 512) {
                int n = tid >> 8, j = tid & 255, b = 2 * P + n;
                v[n * 320 + 64 + j] = (t == 0) ? 0.f
                    : hist[((size_t)(t - 1) * BATCH + b) * HID + j];
            } else if (tid < 640) {
                v[xn * 320 + xj] = xreg;
            }
            __syncthreads();                                     // B2
            float a0 = 0.f, a1 = 0.f;
#pragma unroll
            for (int qq = 0; qq < 10; ++qq) {
                float4 va = *(const float4*)&v[p * 40 + qq * 4];        // uniform bcast
                a0 = fmaf(w[qq * 4 + 0], va.x, a0);
                a0 = fmaf(w[qq * 4 + 1], va.y, a0);
                a0 = fmaf(w[qq * 4 + 2], va.z, a0);
                a0 = fmaf(w[qq * 4 + 3], va.w, a0);
                float4 vb2 = *(const float4*)&v[320 + p * 40 + qq * 4];
                a1 = fmaf(w[qq * 4 + 0], vb2.x, a1);
                a1 = fmaf(w[qq * 4 + 1], vb2.y, a1);
                a1 = fmaf(w[qq * 4 + 2], vb2.z, a1);
                a1 = fmaf(w[qq * 4 + 3], vb2.w, a1);
            }
            pb[tid]        = a0;       // = pb[p*128 + r]
            pb[1024 + tid] = a1;
            if (tid >= 512 && tid < 640 && t + 1 < SEQ) {        // prefetch x[t+1]
                xreg = x[((size_t)(2 * P + xn) * SEQ + (t + 1)) * DIN + xj];
            }
            __syncthreads();                                     // B3
            if (tid < 64) {
                int n = tid >> 5, k = tid & 31, b = 2 * P + n;
                float s0 = bias4[0], s1 = bias4[1], s2 = bias4[2], s3 = bias4[3];
#pragma unroll
                for (int q8 = 0; q8 < 8; ++q8) {
                    int base = n * 1024 + q8 * 128 + k;
                    s0 += pb[base];
                    s1 += pb[base + 32];
                    s2 += pb[base + 64];
                    s3 += pb[base + 96];
                }
                float iv = sigm(s0), fv = sigm(s1), gv = tanh_f(s2), ov = sigm(s3);
                creg = fv * creg + iv * gv;
                float h = ov * tanh_f(creg);
                hist[((size_t)t * BATCH + b) * HID + mem * 32 + k] = h;
            }
            if (tid == 0) {
                __hip_atomic_store(&flagsA[P * 8 + mem], t + 1, __ATOMIC_RELEASE,
                                   __HIP_MEMORY_SCOPE_AGENT);
            }
        }
    } else {
        // ------------------------------ L1 + FC ----------------------------
        const int bxx = blockIdx.x - 256;
        const int mem = bxx >> 4;            // 0..15
        const int g   = bxx & 15;
        const int p   = tid >> 6;            // 0..15 col-chunk (32 wide)
        const int r   = tid & 63;            // local row
        const int row = (r >> 4) * 256 + mem * 16 + (r & 15);

        float w[32];
#pragma unroll
        for (int i = 0; i < 32; ++i) {
            int col = p * 32 + i;
            w[i] = (col < HID) ? Wih1[row * HID + col] : Whh1[row * HID + (col - HID)];
        }
#pragma unroll
        for (int i = 0; i < 32; ++i) asm volatile("" : "+v"(w[i]));

        float bias4[4] = {0.f, 0.f, 0.f, 0.f};
        if (tid < 64) {
            int k = tid & 15;
#pragma unroll
            for (int g4 = 0; g4 < 4; ++g4) {
                int rg = g4 * 256 + mem * 16 + k;
                bias4[g4] = bih1[rg] + bhh1[rg];
            }
        }
        const int nf = mem & 3;              // FC batch within group
        const int c0 = (mem >> 2) * 2;       // FC class base
        float wfc = 0.f;
        if (tid < 512) wfc = Wfc[(c0 + (tid >> 8)) * HID + (tid & 255)];
        asm volatile("" : "+v"(wfc));
        const int   lenb = lengths[4 * g + nf];
        const float bfc0 = bfc[c0], bfc1 = bfc[c0 + 1];
        float creg = 0.f;

        float* vb    = smem;                 // 2048: [n][ h1(256) | h2prev(256) ]
        float* pb    = smem + 2048;          // 4*1032 (n-stride padded +8)
        float* fcred = smem + 6176;          // 8

        for (int t = 0; t < SEQ; ++t) {
            if (tid < 16) {
                int pi = tid >> 3, m = tid & 7;
                waitflag(&flagsA[(2 * g + pi) * 8 + m], t + 1);  // h1[t] ready
            } else if (tid < 32 && t > 0) {
                waitflag(&flagsB[g * 16 + (tid - 16)], t);       // h2[t-1] ready
            }
            __syncthreads();                                     // B1
            {
                int n = tid >> 8, j = tid & 255, b = 4 * g + n;
                vb[n * 512 + j] = hist[((size_t)t * BATCH + b) * HID + j];
                vb[n * 512 + 256 + j] = (t == 0) ? 0.f
                    : xbuf[((size_t)b * 2 + ((t - 1) & 1)) * HID + j];
            }
            __syncthreads();                                     // B2
            float a0 = 0.f, a1 = 0.f, a2 = 0.f, a3 = 0.f;
#pragma unroll
            for (int qq = 0; qq < 8; ++qq) {
                int base = p * 32 + qq * 4;
                float4 v0 = *(const float4*)&vb[base];
                a0 = fmaf(w[qq * 4 + 0], v0.x, a0); a0 = fmaf(w[qq * 4 + 1], v0.y, a0);
                a0 = fmaf(w[qq * 4 + 2], v0.z, a0); a0 = fmaf(w[qq * 4 + 3], v0.w, a0);
                float4 v1 = *(const float4*)&vb[512 + base];
                a1 = fmaf(w[qq * 4 + 0], v1.x, a1); a1 = fmaf(w[qq * 4 + 1], v1.y, a1);
                a1 = fmaf(w[qq * 4 + 2], v1.z, a1); a1 = fmaf(w[qq * 4 + 3], v1.w, a1);
                float4 v2 = *(const float4*)&vb[1024 + base];
                a2 = fmaf(w[qq * 4 + 0], v2.x, a2); a2 = fmaf(w[qq * 4 + 1], v2.y, a2);
                a2 = fmaf(w[qq * 4 + 2], v2.z, a2); a2 = fmaf(w[qq * 4 + 3], v2.w, a2);
                float4 v3 = *(const float4*)&vb[1536 + base];
                a3 = fmaf(w[qq * 4 + 0], v3.x, a3); a3 = fmaf(w[qq * 4 + 1], v3.y, a3);
                a3 = fmaf(w[qq * 4 + 2], v3.z, a3); a3 = fmaf(w[qq * 4 + 3], v3.w, a3);
            }
            pb[tid]            = a0;         // = pb[n*1032 + p*64 + r], n=0
            pb[1032 + tid]     = a1;
            pb[2064 + tid]     = a2;
            pb[3096 + tid]     = a3;
            // FC for step t-1 (vb h2-half == h2[t-1]), overlapped pre-barrier
            float fval = 0.f;
            if (t > 0 && tid < 512) {
                fval = vb[nf * 512 + 256 + (tid & 255)] * wfc;
                fval += __shfl_xor(fval, 1);
                fval += __shfl_xor(fval, 2);
                fval += __shfl_xor(fval, 4);
                fval += __shfl_xor(fval, 8);
                fval += __shfl_xor(fval, 16);
                fval += __shfl_xor(fval, 32);
                if ((tid & 63) == 0) fcred[tid >> 6] = fval;
            }
            __syncthreads();                                     // B3
            if (tid < 64) {
                int n = tid >> 4, k = tid & 15, b = 4 * g + n;
                float s0 = bias4[0], s1 = bias4[1], s2 = bias4[2], s3 = bias4[3];
#pragma unroll
                for (int q16 = 0; q16 < 16; ++q16) {
                    int base = n * 1032 + q16 * 64 + k;
                    s0 += pb[base];
                    s1 += pb[base + 16];
                    s2 += pb[base + 32];
                    s3 += pb[base + 48];
                }
                float iv = sigm(s0), fv = sigm(s1), gv = tanh_f(s2), ov = sigm(s3);
                creg = fv * creg + iv * gv;
                float h = ov * tanh_f(creg);
                xbuf[((size_t)b * 2 + (t & 1)) * HID + mem * 16 + k] = h;
            } else if (tid < 66 && t > 0 && (t - 1) < lenb) {
                int cls = tid - 64;
                float s2 = fcred[cls * 4 + 0] + fcred[cls * 4 + 1]
                         + fcred[cls * 4 + 2] + fcred[cls * 4 + 3];
                out[((size_t)(4 * g + nf) * SEQ + (t - 1)) * NCLS + c0 + cls]
                    = (cls ? bfc1 : bfc0) + s2;
            }
            if (tid == 0) {
                __hip_atomic_store(&flagsB[g * 16 + mem], t + 1, __ATOMIC_RELEASE,
                                   __HIP_MEMORY_SCOPE_AGENT);
            }
        }
        // tail: FC for t = SEQ-1
        if (tid < 16) waitflag(&flagsB[g * 16 + tid], SEQ);
        __syncthreads();
        float fval = 0.f;
        if (tid < 512) {
            int b = 4 * g + nf;
            float hv = xbuf[((size_t)b * 2 + ((SEQ - 1) & 1)) * HID + (tid & 255)];
            fval = hv * wfc;
            fval += __shfl_xor(fval, 1);
            fval += __shfl_xor(fval, 2);
            fval += __shfl_xor(fval, 4);
            fval += __shfl_xor(fval, 8);
            fval += __shfl_xor(fval, 16);
            fval += __shfl_xor(fval, 32);
            if ((tid & 63) == 0) fcred[tid >> 6] = fval;
        }
        __syncthreads();
        if (tid < 2 && (SEQ - 1) < lenb) {
            float s2 = fcred[tid * 4 + 0] + fcred[tid * 4 + 1]
                     + fcred[tid * 4 + 2] + fcred[tid * 4 + 3];
            out[((size_t)(4 * g + nf) * SEQ + (SEQ - 1)) * NCLS + c0 + tid]
                = (tid ? bfc1 : bfc0) + s2;
        }
    }
}

// ---------------------------------------------------------------------------
extern "C" void kernel_launch(void* const* d_in, const int* in_sizes, int n_in,
                              void* d_out, int out_size, void* d_ws, size_t ws_size,
                              hipStream_t stream) {
    (void)in_sizes; (void)n_in; (void)out_size;
    const float* x     = (const float*)d_in[0];
    const int*   lens  = (const int*)  d_in[1];
    const float* Wih0  = (const float*)d_in[2];
    const float* Whh0  = (const float*)d_in[3];
    const float* bih0  = (const float*)d_in[4];
    const float* bhh0  = (const float*)d_in[5];
    const float* Wih1  = (const float*)d_in[6];
    const float* Whh1  = (const float*)d_in[7];
    const float* bih1  = (const float*)d_in[8];
    const float* bhh1  = (const float*)d_in[9];
    const float* Wfc   = (const float*)d_in[10];
    const float* bfc   = (const float*)d_in[11];
    float* out = (float*)d_out;
    char*  ws  = (char*)d_ws;

    // ws: flagsA(1KB) | flagsB(1KB) | xbuf(128KB) | hist(128MiB)
    int*   flagsA = (int*)(ws);
    int*   flagsB = (int*)(ws + 1024);
    float* xbuf   = (float*)(ws + 2048);
    const size_t hist_off = 2048 + (size_t)BATCH * 2 * HID * 4;   // 133120
    float* hist = (float*)(ws + hist_off);
    const size_t need = hist_off + (size_t)SEQ * BATCH * HID * 4;
    if (ws_size < need) return;

    hipMemsetAsync(ws, 0, 2048, stream);   // zero flags each launch
    init_out_kernel<<<(BATCH * SEQ * NCLS + 255) / 256, 256, 0, stream>>>(out, bfc);
    lstm_fused_kernel<<<512, 1024, 0, stream>>>(x, Wih0, Whh0, bih0, bhh0,
                                                Wih1, Whh1, bih1, bhh1,
                                                Wfc, bfc, lens, out,
                                                hist, xbuf, flagsA, flagsB);
}

// Round 7
// 30520.526 us; speedup vs baseline: 1.0045x; 1.0045x over previous
//
#include <hip/hip_runtime.h>
#include <hip/hip_bf16.h>

#define BATCH 64
#define SEQ   2048
#define DIN   64
#define HID   256
#define NCLS  8

__device__ __forceinline__ float sigm(float x)  { return 1.0f / (1.0f + __expf(-x)); }
__device__ __forceinline__ float tanh_f(float x){ return 1.0f - 2.0f / (__expf(2.0f * x) + 1.0f); }

// Self-tagged publication: low 3 mantissa bits carry the step tag (<=7 ulp
// distortion ~1e-6 rel). Tag+value share one dword -> a single relaxed
// agent-scope atomic load returns data AND readiness in one fabric round trip.
__device__ __forceinline__ float tagf(float v, unsigned tag) {
    return __uint_as_float((__float_as_uint(v) & ~7u) | tag);
}
__device__ __forceinline__ int tagok(float v, unsigned tag) {
    return (__float_as_uint(v) & 7u) == tag;
}

// out[b][t][c] = bfc[c]; FC overwrites t < len, so t >= len keeps exactly bfc.
__global__ void init_out_kernel(float* __restrict__ out, const float* __restrict__ bfc) {
    int idx = blockIdx.x * blockDim.x + threadIdx.x;
    if (idx < BATCH * SEQ * NCLS) out[idx] = bfc[idx & 7];
}

// ---------------------------------------------------------------------------
// L0: 256 blocks = mem(8) x pair(32); block serves batches {2P,2P+1}.
// 128 gate rows/block, w0[40]/thread (VGPR-resident, round-5 proven).
// Per step: [FMA -> pbuf] B1 [exchange phase: reducers finish state t and
// publish tagged h to ring0 (relaxed agent atomic) + plain h to hist (for L1);
// loaders retry-load peers' tagged h; x-writers commit prefetched x] B2.
// No flags, no release/acquire, no producer back-pressure.
// ---------------------------------------------------------------------------
__global__ __launch_bounds__(1024) void lstm_l0_kernel(
    const float* __restrict__ x,    const float* __restrict__ Wih0,
    const float* __restrict__ Whh0, const float* __restrict__ bih0,
    const float* __restrict__ bhh0, float* __restrict__ hist,
    float* __restrict__ ring0)
{
    const int P   = blockIdx.x & 31;
    const int mem = blockIdx.x >> 5;       // 0..7
    const int tid = threadIdx.x;
    const int p   = tid >> 7;              // 0..7 col-chunk (40 wide), wave-uniform
    const int r   = tid & 127;
    const int row = (r >> 5) * 256 + mem * 32 + (r & 31);

    float w[40];
#pragma unroll
    for (int q = 0; q < 40; ++q) {
        int col = p * 40 + q;
        w[q] = (col < DIN) ? Wih0[row * DIN + col] : Whh0[row * HID + (col - DIN)];
    }
#pragma unroll
    for (int q = 0; q < 40; ++q) asm volatile("" : "+v"(w[q]));

    const int isRed = (tid < 64);                       // n=tid>>5, k=tid&31
    const int isLd  = (tid >= 64 && tid < 512);         // 448 peer-slot loaders
    const int isXw  = (tid >= 512 && tid < 544);        // 32 x float4 writers

    float bias4[4] = {0.f, 0.f, 0.f, 0.f};
    if (isRed) {
        int k = tid & 31;
#pragma unroll
        for (int g4 = 0; g4 < 4; ++g4) {
            int rg = g4 * 256 + mem * 32 + k;
            bias4[g4] = bih0[rg] + bhh0[rg];
        }
    }
    float creg = 0.f;

    int ln = 0, lj = 0;
    if (isLd) {                                         // fixed (batch, j) per lane
        int i = tid - 64;
        ln = (i >= 224);
        int jj = i - (ln ? 224 : 0);
        lj = jj + (jj >= mem * 32 ? 32 : 0);            // skip own 32-slice
    }
    int xn = 0, xc = 0;
    float4 xreg = make_float4(0.f, 0.f, 0.f, 0.f);
    if (isXw) { xn = (tid - 512) >> 4; xc = (tid & 15) * 4; }

    __shared__ __align__(16) float v[640];    // [n][ x(64) | h1prev(256) ]
    __shared__ float pb[2048];                // [n][p][r]

    // prologue (t=0): h-prev = 0, x[0]
    if (isRed) v[(tid >> 5) * 320 + 64 + mem * 32 + (tid & 31)] = 0.f;
    if (isLd)  v[ln * 320 + 64 + lj] = 0.f;
    if (isXw)  *(float4*)&v[xn * 320 + xc] =
        *(const float4*)&x[((size_t)(2 * P + xn) * SEQ) * DIN + xc];
    __syncthreads();

    for (int t = 0; t < SEQ; ++t) {
        float a0 = 0.f, a1 = 0.f;
#pragma unroll
        for (int qq = 0; qq < 10; ++qq) {
            float4 va = *(const float4*)&v[p * 40 + qq * 4];        // uniform bcast
            a0 = fmaf(w[qq * 4 + 0], va.x, a0); a0 = fmaf(w[qq * 4 + 1], va.y, a0);
            a0 = fmaf(w[qq * 4 + 2], va.z, a0); a0 = fmaf(w[qq * 4 + 3], va.w, a0);
            float4 vb2 = *(const float4*)&v[320 + p * 40 + qq * 4];
            a1 = fmaf(w[qq * 4 + 0], vb2.x, a1); a1 = fmaf(w[qq * 4 + 1], vb2.y, a1);
            a1 = fmaf(w[qq * 4 + 2], vb2.z, a1); a1 = fmaf(w[qq * 4 + 3], vb2.w, a1);
        }
        if (isXw && t + 1 < SEQ)                       // prefetch x[t+1]
            xreg = *(const float4*)&x[((size_t)(2 * P + xn) * SEQ + (t + 1)) * DIN + xc];
        pb[tid]        = a0;
        pb[1024 + tid] = a1;
        __syncthreads();                               // B1

        // exchange phase: finish state t, stage v for t+1
        if (isRed) {
            int n = tid >> 5, k = tid & 31, b = 2 * P + n;
            float s0 = bias4[0], s1 = bias4[1], s2 = bias4[2], s3 = bias4[3];
#pragma unroll
            for (int q8 = 0; q8 < 8; ++q8) {
                int base = n * 1024 + q8 * 128 + k;
                s0 += pb[base];       s1 += pb[base + 32];
                s2 += pb[base + 64];  s3 += pb[base + 96];
            }
            float iv = sigm(s0), fv = sigm(s1), gv = tanh_f(s2), ov = sigm(s3);
            creg = fv * creg + iv * gv;
            float h = ov * tanh_f(creg);
            hist[((size_t)t * BATCH + b) * HID + mem * 32 + k] = h;   // plain, for L1
            if (t + 1 < SEQ) {
                v[n * 320 + 64 + mem * 32 + k] = h;                   // own slice local
                __hip_atomic_store(&ring0[(((size_t)(t & 3)) * BATCH + b) * HID + mem * 32 + k],
                                   tagf(h, (unsigned)((t + 1) & 7)),
                                   __ATOMIC_RELAXED, __HIP_MEMORY_SCOPE_AGENT);
            }
        } else if (isLd) {
            if (t + 1 < SEQ) {
                float* src = &ring0[(((size_t)(t & 3)) * BATCH + (2 * P + ln)) * HID + lj];
                const unsigned want = (unsigned)((t + 1) & 7);
                float hv; int ok;
                do {
                    hv = __hip_atomic_load(src, __ATOMIC_RELAXED, __HIP_MEMORY_SCOPE_AGENT);
                    ok = tagok(hv, want);
                } while (!__all(ok));
                v[ln * 320 + 64 + lj] = hv;
            }
        } else if (isXw) {
            if (t + 1 < SEQ) *(float4*)&v[xn * 320 + xc] = xreg;
        }
        __syncthreads();                               // B2
    }
}

// ---------------------------------------------------------------------------
// L1 + FC: 256 blocks = mem(16) x group(16); block serves batches 4g..4g+3.
// 64 gate rows/block, w1[32]/thread. h1[t] plain-loaded from hist (L0 done;
// prefetched one step ahead into registers). h2 exchange via tagged ring1.
// FC(t-1) overlapped pre-barrier from the vb h2-half; no atomics on out.
// ---------------------------------------------------------------------------
__global__ __launch_bounds__(1024) void lstm_l1_kernel(
    const float* __restrict__ hist, const float* __restrict__ Wih1,
    const float* __restrict__ Whh1, const float* __restrict__ bih1,
    const float* __restrict__ bhh1, const float* __restrict__ Wfc,
    const float* __restrict__ bfc,  const int* __restrict__ lengths,
    float* __restrict__ out, float* __restrict__ ring1)
{
    const int g   = blockIdx.x & 15;
    const int mem = blockIdx.x >> 4;       // 0..15
    const int tid = threadIdx.x;
    const int p   = tid >> 6;              // 0..15 col-chunk (32 wide), wave-uniform
    const int r   = tid & 63;
    const int row = (r >> 4) * 256 + mem * 16 + (r & 15);

    float w[32];
#pragma unroll
    for (int q = 0; q < 32; ++q) {
        int col = p * 32 + q;
        w[q] = (col < HID) ? Wih1[row * HID + col] : Whh1[row * HID + (col - HID)];
    }
#pragma unroll
    for (int q = 0; q < 32; ++q) asm volatile("" : "+v"(w[q]));

    float bias4[4] = {0.f, 0.f, 0.f, 0.f};
    if (tid < 64) {
        int k = tid & 15;
#pragma unroll
        for (int g4 = 0; g4 < 4; ++g4) {
            int rg = g4 * 256 + mem * 16 + k;
            bias4[g4] = bih1[rg] + bhh1[rg];
        }
    }
    float creg = 0.f;

    const int nf = mem & 3;                // FC batch within group
    const int c0 = (mem >> 2) * 2;         // FC class base
    float wfc = 0.f;
    if (tid < 512) wfc = Wfc[(c0 + (tid >> 8)) * HID + (tid & 255)];
    asm volatile("" : "+v"(wfc));
    const int   lenb = lengths[4 * g + nf];
    const float bfc0 = bfc[c0], bfc1 = bfc[c0 + 1];

    // roles: reducers tid<64; loaders tid>=64 (960 lanes, 1 h2 dword each);
    // h1-writers tid in [544,800) (256 lanes, float4) double as loaders.
    int ln = 0, lj = 0;
    if (tid >= 64) {
        int i = tid - 64;
        ln = i / 240;
        int jj = i - ln * 240;
        lj = jj + (jj >= mem * 16 ? 16 : 0);            // skip own 16-slice
    }
    const int isHw = (tid >= 544 && tid < 800);
    int hn = 0, hc = 0;
    float4 hreg = make_float4(0.f, 0.f, 0.f, 0.f);
    if (isHw) { hn = (tid - 544) >> 6; hc = ((tid - 544) & 63) * 4; }

    __shared__ __align__(16) float vb[2048];  // [n][ h1(256) | h2prev(256) ]
    __shared__ float pb[4128];                // [n] stride 1032 (pad +8)
    __shared__ float fcred[8];

    // prologue: vb = { h1[0], h2=0 }
    if (isHw) *(float4*)&vb[hn * 512 + hc] =
        *(const float4*)&hist[((size_t)0 * BATCH + 4 * g + hn) * HID + hc];
    if (tid < 64) vb[(tid >> 4) * 512 + 256 + mem * 16 + (tid & 15)] = 0.f;
    if (tid >= 64) vb[ln * 512 + 256 + lj] = 0.f;
    __syncthreads();

    for (int t = 0; t < SEQ; ++t) {
        float a0 = 0.f, a1 = 0.f, a2 = 0.f, a3 = 0.f;
#pragma unroll
        for (int qq = 0; qq < 8; ++qq) {
            int base = p * 32 + qq * 4;
            float4 v0 = *(const float4*)&vb[base];
            a0 = fmaf(w[qq * 4 + 0], v0.x, a0); a0 = fmaf(w[qq * 4 + 1], v0.y, a0);
            a0 = fmaf(w[qq * 4 + 2], v0.z, a0); a0 = fmaf(w[qq * 4 + 3], v0.w, a0);
            float4 v1 = *(const float4*)&vb[512 + base];
            a1 = fmaf(w[qq * 4 + 0], v1.x, a1); a1 = fmaf(w[qq * 4 + 1], v1.y, a1);
            a1 = fmaf(w[qq * 4 + 2], v1.z, a1); a1 = fmaf(w[qq * 4 + 3], v1.w, a1);
            float4 v2 = *(const float4*)&vb[1024 + base];
            a2 = fmaf(w[qq * 4 + 0], v2.x, a2); a2 = fmaf(w[qq * 4 + 1], v2.y, a2);
            a2 = fmaf(w[qq * 4 + 2], v2.z, a2); a2 = fmaf(w[qq * 4 + 3], v2.w, a2);
            float4 v3 = *(const float4*)&vb[1536 + base];
            a3 = fmaf(w[qq * 4 + 0], v3.x, a3); a3 = fmaf(w[qq * 4 + 1], v3.y, a3);
            a3 = fmaf(w[qq * 4 + 2], v3.z, a3); a3 = fmaf(w[qq * 4 + 3], v3.w, a3);
        }
        if (isHw && t + 1 < SEQ)                       // prefetch h1[t+1]
            hreg = *(const float4*)&hist[((size_t)(t + 1) * BATCH + 4 * g + hn) * HID + hc];
        pb[p * 64 + r]        = a0;
        pb[1032 + p * 64 + r] = a1;
        pb[2064 + p * 64 + r] = a2;
        pb[3096 + p * 64 + r] = a3;
        // FC partial for step t-1 (vb h2-half holds h2[t-1])
        float fval = 0.f;
        if (t > 0 && tid < 512) {
            fval = vb[nf * 512 + 256 + (tid & 255)] * wfc;
            fval += __shfl_xor(fval, 1);
            fval += __shfl_xor(fval, 2);
            fval += __shfl_xor(fval, 4);
            fval += __shfl_xor(fval, 8);
            fval += __shfl_xor(fval, 16);
            fval += __shfl_xor(fval, 32);
            if ((tid & 63) == 0) fcred[tid >> 6] = fval;
        }
        __syncthreads();                               // B1

        // exchange phase
        if (tid < 64) {
            int n = tid >> 4, k = tid & 15, b = 4 * g + n;
            float s0 = bias4[0], s1 = bias4[1], s2 = bias4[2], s3 = bias4[3];
#pragma unroll
            for (int q16 = 0; q16 < 16; ++q16) {
                int base = n * 1032 + q16 * 64 + k;
                s0 += pb[base];       s1 += pb[base + 16];
                s2 += pb[base + 32];  s3 += pb[base + 48];
            }
            float iv = sigm(s0), fv = sigm(s1), gv = tanh_f(s2), ov = sigm(s3);
            creg = fv * creg + iv * gv;
            float h = ov * tanh_f(creg);
            vb[n * 512 + 256 + mem * 16 + k] = h;      // own slice local
            __hip_atomic_store(&ring1[(((size_t)(t & 3)) * BATCH + b) * HID + mem * 16 + k],
                               tagf(h, (unsigned)((t + 1) & 7)),
                               __ATOMIC_RELAXED, __HIP_MEMORY_SCOPE_AGENT);
        } else {
            if ((tid == 64 || tid == 65) && t > 0 && (t - 1) < lenb) {
                int cls = tid - 64;
                float s2 = fcred[cls * 4 + 0] + fcred[cls * 4 + 1]
                         + fcred[cls * 4 + 2] + fcred[cls * 4 + 3];
                out[((size_t)(4 * g + nf) * SEQ + (t - 1)) * NCLS + c0 + cls]
                    = (cls ? bfc1 : bfc0) + s2;
            }
            if (isHw && t + 1 < SEQ) *(float4*)&vb[hn * 512 + hc] = hreg;
            // h2[t] tagged retry-load (runs for every t incl. last, for final FC)
            {
                float* src = &ring1[(((size_t)(t & 3)) * BATCH + (4 * g + ln)) * HID + lj];
                const unsigned want = (unsigned)((t + 1) & 7);
                float hv; int ok;
                do {
                    hv = __hip_atomic_load(src, __ATOMIC_RELAXED, __HIP_MEMORY_SCOPE_AGENT);
                    ok = tagok(hv, want);
                } while (!__all(ok));
                vb[ln * 512 + 256 + lj] = hv;
            }
        }
        __syncthreads();                               // B2
    }

    // epilogue: FC for t = SEQ-1 (vb h2-half now holds h2[SEQ-1])
    float fval = 0.f;
    if (tid < 512) {
        fval = vb[nf * 512 + 256 + (tid & 255)] * wfc;
        fval += __shfl_xor(fval, 1);
        fval += __shfl_xor(fval, 2);
        fval += __shfl_xor(fval, 4);
        fval += __shfl_xor(fval, 8);
        fval += __shfl_xor(fval, 16);
        fval += __shfl_xor(fval, 32);
        if ((tid & 63) == 0) fcred[tid >> 6] = fval;
    }
    __syncthreads();
    if (tid < 2 && (SEQ - 1) < lenb) {
        float s2 = fcred[tid * 4 + 0] + fcred[tid * 4 + 1]
                 + fcred[tid * 4 + 2] + fcred[tid * 4 + 3];
        out[((size_t)(4 * g + nf) * SEQ + (SEQ - 1)) * NCLS + c0 + tid]
            = (tid ? bfc1 : bfc0) + s2;
    }
}

// ---------------------------------------------------------------------------
extern "C" void kernel_launch(void* const* d_in, const int* in_sizes, int n_in,
                              void* d_out, int out_size, void* d_ws, size_t ws_size,
                              hipStream_t stream) {
    (void)in_sizes; (void)n_in; (void)out_size;
    const float* x     = (const float*)d_in[0];
    const int*   lens  = (const int*)  d_in[1];
    const float* Wih0  = (const float*)d_in[2];
    const float* Whh0  = (const float*)d_in[3];
    const float* bih0  = (const float*)d_in[4];
    const float* bhh0  = (const float*)d_in[5];
    const float* Wih1  = (const float*)d_in[6];
    const float* Whh1  = (const float*)d_in[7];
    const float* bih1  = (const float*)d_in[8];
    const float* bhh1  = (const float*)d_in[9];
    const float* Wfc   = (const float*)d_in[10];
    const float* bfc   = (const float*)d_in[11];
    float* out = (float*)d_out;
    char*  ws  = (char*)d_ws;

    // ws: ring0(256KB) | ring1(256KB) | hist(128MiB)
    const size_t RING = (size_t)4 * BATCH * HID * 4;   // 256 KB
    float* ring0 = (float*)(ws);
    float* ring1 = (float*)(ws + RING);
    float* hist  = (float*)(ws + 2 * RING);
    const size_t need = 2 * RING + (size_t)SEQ * BATCH * HID * 4;
    if (ws_size < need) return;

    // rings must be zero so no stale/poison dword can alias a valid tag
    hipMemsetAsync(ws, 0, 2 * RING, stream);
    init_out_kernel<<<(BATCH * SEQ * NCLS + 255) / 256, 256, 0, stream>>>(out, bfc);
    lstm_l0_kernel<<<256, 1024, 0, stream>>>(x, Wih0, Whh0, bih0, bhh0, hist, ring0);
    lstm_l1_kernel<<<256, 1024, 0, stream>>>(hist, Wih1, Whh1, bih1, bhh1, Wfc, bfc,
                                             lens, out, ring1);
}

// Round 8
// 29575.061 us; speedup vs baseline: 1.0366x; 1.0320x over previous
//
#include <hip/hip_runtime.h>
#include <hip/hip_bf16.h>

#define BATCH 64
#define SEQ   2048
#define DIN   64
#define HID   256
#define NCLS  8

__device__ __forceinline__ float sigm(float x)  { return 1.0f / (1.0f + __expf(-x)); }
__device__ __forceinline__ float tanh_f(float x){ return 1.0f - 2.0f / (__expf(2.0f * x) + 1.0f); }

// Self-tagged publication: low 3 mantissa bits carry the step tag (<=7 ulp,
// ~1e-6 rel). Tag+value share one dword -> one relaxed agent-scope atomic
// load returns data AND readiness in a single L3 round trip. No fences ever
// (fences were the 4-5us/step in rounds 1-5: agent-release => L2 writeback).
__device__ __forceinline__ float tagf(float v, unsigned tag) {
    return __uint_as_float((__float_as_uint(v) & ~7u) | tag);
}
__device__ __forceinline__ int tagok(float v, unsigned tag) {
    return (__float_as_uint(v) & 7u) == tag;
}
__device__ __forceinline__ float aload(float* p) {
    return __hip_atomic_load(p, __ATOMIC_RELAXED, __HIP_MEMORY_SCOPE_AGENT);
}
__device__ __forceinline__ void astore(float* p, float v) {
    __hip_atomic_store(p, v, __ATOMIC_RELAXED, __HIP_MEMORY_SCOPE_AGENT);
}

// out[b][t][c] = bfc[c]; FC overwrites t < len, so t >= len keeps exactly bfc.
__global__ void init_out_kernel(float* __restrict__ out, const float* __restrict__ bfc) {
    int idx = blockIdx.x * blockDim.x + threadIdx.x;
    if (idx < BATCH * SEQ * NCLS) out[idx] = bfc[idx & 7];
}

// ---------------------------------------------------------------------------
// L0: 256 blocks = mem(8) x pair(32); block serves batches {2P,2P+1}.
// Roles: tid<64 reducer (+14 sentinel lanes); 64..511 bulk loaders;
// 544..575 x float4 writers. Round-8 sync: sentinels poll ONE word per
// producer slice with s_sleep backoff (spin traffic ~0), then set LDS go;
// loaders spin on LDS, then ONE bulk L3 load + per-lane tag verify.
// ---------------------------------------------------------------------------
__global__ __launch_bounds__(1024) void lstm_l0_kernel(
    const float* __restrict__ x,    const float* __restrict__ Wih0,
    const float* __restrict__ Whh0, const float* __restrict__ bih0,
    const float* __restrict__ bhh0, float* __restrict__ hist,
    float* __restrict__ ring0)
{
    const int P   = blockIdx.x & 31;
    const int mem = blockIdx.x >> 5;       // 0..7
    const int tid = threadIdx.x;
    const int p   = tid >> 7;              // 0..7 col-chunk (40 wide), wave-uniform
    const int r   = tid & 127;
    const int row = (r >> 5) * 256 + mem * 32 + (r & 31);
    const int BH  = BATCH * HID;

    float w[40];
#pragma unroll
    for (int q = 0; q < 40; ++q) {
        int col = p * 40 + q;
        w[q] = (col < DIN) ? Wih0[row * DIN + col] : Whh0[row * HID + (col - DIN)];
    }
#pragma unroll
    for (int q = 0; q < 40; ++q) asm volatile("" : "+v"(w[q]));

    const int isRed = (tid < 64);
    const int isLd  = (tid >= 64 && tid < 512);         // 448 loaders
    const int isXw  = (tid >= 544 && tid < 576);        // 32 x float4 writers

    float bias4[4] = {0.f, 0.f, 0.f, 0.f};
    if (isRed) {
        int k = tid & 31;
#pragma unroll
        for (int g4 = 0; g4 < 4; ++g4) {
            int rg = g4 * 256 + mem * 32 + k;
            bias4[g4] = bih0[rg] + bhh0[rg];
        }
    }
    float creg = 0.f;

    // sentinel lane mapping (reducer wave, lanes 0..13): peer pm, batch n
    int spm = 0, sn = 0;
    if (tid < 14) {
        spm = tid >> 1; spm += (spm >= mem);
        sn  = tid & 1;
    }
    int ln = 0, lj = 0;
    if (isLd) {
        int i = tid - 64;
        ln = (i >= 224);
        int jj = i - (ln ? 224 : 0);
        lj = jj + (jj >= mem * 32 ? 32 : 0);            // skip own 32-slice
    }
    int xn = 0, xc = 0;
    float4 xreg = make_float4(0.f, 0.f, 0.f, 0.f);
    if (isXw) { xn = (tid - 544) >> 4; xc = ((tid - 544) & 15) * 4; }

    __shared__ __align__(16) float v[640];    // [n][ x(64) | h1prev(256) ]
    __shared__ float pb[2048];                // [n][p][r]
    __shared__ int go;

    if (tid == 0) go = 0;
    if (isRed) v[(tid >> 5) * 320 + 64 + mem * 32 + (tid & 31)] = 0.f;
    if (isLd)  v[ln * 320 + 64 + lj] = 0.f;
    if (isXw)  *(float4*)&v[xn * 320 + xc] =
        *(const float4*)&x[((size_t)(2 * P + xn) * SEQ) * DIN + xc];
    __syncthreads();

    for (int t = 0; t < SEQ; ++t) {
        float a0 = 0.f, a1 = 0.f;
#pragma unroll
        for (int qq = 0; qq < 10; ++qq) {
            float4 va = *(const float4*)&v[p * 40 + qq * 4];        // uniform bcast
            a0 = fmaf(w[qq * 4 + 0], va.x, a0); a0 = fmaf(w[qq * 4 + 1], va.y, a0);
            a0 = fmaf(w[qq * 4 + 2], va.z, a0); a0 = fmaf(w[qq * 4 + 3], va.w, a0);
            float4 vb2 = *(const float4*)&v[320 + p * 40 + qq * 4];
            a1 = fmaf(w[qq * 4 + 0], vb2.x, a1); a1 = fmaf(w[qq * 4 + 1], vb2.y, a1);
            a1 = fmaf(w[qq * 4 + 2], vb2.z, a1); a1 = fmaf(w[qq * 4 + 3], vb2.w, a1);
        }
        if (isXw && t + 1 < SEQ)
            xreg = *(const float4*)&x[((size_t)(2 * P + xn) * SEQ + (t + 1)) * DIN + xc];
        pb[tid]        = a0;
        pb[1024 + tid] = a1;
        __syncthreads();                               // B1

        const int slot = t & 3;
        const unsigned want = (unsigned)((t + 1) & 7);
        if (isRed) {
            int n = tid >> 5, k = tid & 31, b = 2 * P + n;
            float s0 = bias4[0], s1 = bias4[1], s2 = bias4[2], s3 = bias4[3];
#pragma unroll
            for (int q8 = 0; q8 < 8; ++q8) {
                int base = n * 1024 + q8 * 128 + k;
                s0 += pb[base];       s1 += pb[base + 32];
                s2 += pb[base + 64];  s3 += pb[base + 96];
            }
            float iv = sigm(s0), fv = sigm(s1), gv = tanh_f(s2), ov = sigm(s3);
            creg = fv * creg + iv * gv;
            float h = ov * tanh_f(creg);
            hist[((size_t)t * BATCH + b) * HID + mem * 32 + k] = h;   // plain, for L1
            if (t + 1 < SEQ) {
                v[n * 320 + 64 + mem * 32 + k] = h;                   // own slice
                astore(&ring0[((size_t)slot * BATCH + b) * HID + mem * 32 + k],
                       tagf(h, want));
                // sentinel poll: lanes 0..13, one word per peer slice
                bool ok = (tid >= 14);
                float* saddr = &ring0[((size_t)slot * BATCH + (2 * P + sn)) * HID + spm * 32 + 31];
                for (;;) {
                    if (!ok) ok = tagok(aload(saddr), want);
                    if (__all(ok)) break;
                    __builtin_amdgcn_s_sleep(1);
                }
                if (tid == 0)
                    __hip_atomic_store(&go, t + 1, __ATOMIC_RELAXED,
                                       __HIP_MEMORY_SCOPE_WORKGROUP);
            }
        } else if (isLd) {
            if (t + 1 < SEQ) {
                while (__hip_atomic_load(&go, __ATOMIC_RELAXED,
                                         __HIP_MEMORY_SCOPE_WORKGROUP) < t + 1)
                    __builtin_amdgcn_s_sleep(1);
                float* src = &ring0[((size_t)slot * BATCH + (2 * P + ln)) * HID + lj];
                float hv = aload(src);
                while (!tagok(hv, want)) { __builtin_amdgcn_s_sleep(1); hv = aload(src); }
                v[ln * 320 + 64 + lj] = hv;
            }
        } else if (isXw) {
            if (t + 1 < SEQ) *(float4*)&v[xn * 320 + xc] = xreg;
        }
        __syncthreads();                               // B2
    }
}

// ---------------------------------------------------------------------------
// L1 + FC: 256 blocks = mem(16) x group(16); block serves batches 4g..4g+3.
// Roles: tid<64 reducer (+60 sentinel lanes); 64..1023 loaders (1 word each);
// 544..799 double as h1 float4 writers (prefetched). Same sentinel/go sync.
// FC(t-1) overlapped pre-barrier; plain stores to out (exclusive ownership).
// ---------------------------------------------------------------------------
__global__ __launch_bounds__(1024) void lstm_l1_kernel(
    const float* __restrict__ hist, const float* __restrict__ Wih1,
    const float* __restrict__ Whh1, const float* __restrict__ bih1,
    const float* __restrict__ bhh1, const float* __restrict__ Wfc,
    const float* __restrict__ bfc,  const int* __restrict__ lengths,
    float* __restrict__ out, float* __restrict__ ring1)
{
    const int g   = blockIdx.x & 15;
    const int mem = blockIdx.x >> 4;       // 0..15
    const int tid = threadIdx.x;
    const int p   = tid >> 6;              // 0..15 col-chunk (32 wide), wave-uniform
    const int r   = tid & 63;
    const int row = (r >> 4) * 256 + mem * 16 + (r & 15);

    float w[32];
#pragma unroll
    for (int q = 0; q < 32; ++q) {
        int col = p * 32 + q;
        w[q] = (col < HID) ? Wih1[row * HID + col] : Whh1[row * HID + (col - HID)];
    }
#pragma unroll
    for (int q = 0; q < 32; ++q) asm volatile("" : "+v"(w[q]));

    float bias4[4] = {0.f, 0.f, 0.f, 0.f};
    if (tid < 64) {
        int k = tid & 15;
#pragma unroll
        for (int g4 = 0; g4 < 4; ++g4) {
            int rg = g4 * 256 + mem * 16 + k;
            bias4[g4] = bih1[rg] + bhh1[rg];
        }
    }
    float creg = 0.f;

    const int nf = mem & 3;                // FC batch within group
    const int c0 = (mem >> 2) * 2;         // FC class base
    float wfc = 0.f;
    if (tid < 512) wfc = Wfc[(c0 + (tid >> 8)) * HID + (tid & 255)];
    asm volatile("" : "+v"(wfc));
    const int   lenb = lengths[4 * g + nf];
    const float bfc0 = bfc[c0], bfc1 = bfc[c0 + 1];

    // sentinel lanes 0..59 of reducer wave: peer pm (15), batch n (4)
    int spm = 0, sn = 0;
    if (tid < 60) {
        spm = tid >> 2; spm += (spm >= mem);
        sn  = tid & 3;
    }
    int ln = 0, lj = 0;
    if (tid >= 64) {
        int i = tid - 64;
        ln = i / 240;
        int jj = i - ln * 240;
        lj = jj + (jj >= mem * 16 ? 16 : 0);            // skip own 16-slice
    }
    const int isHw = (tid >= 544 && tid < 800);
    int hn = 0, hc = 0;
    float4 hreg = make_float4(0.f, 0.f, 0.f, 0.f);
    if (isHw) { hn = (tid - 544) >> 6; hc = ((tid - 544) & 63) * 4; }

    __shared__ __align__(16) float vb[2048];  // [n][ h1(256) | h2prev(256) ]
    __shared__ float pb[4128];                // [n] stride 1032 (pad +8)
    __shared__ float fcred[8];
    __shared__ int go;

    if (tid == 0) go = 0;
    if (isHw) *(float4*)&vb[hn * 512 + hc] =
        *(const float4*)&hist[((size_t)0 * BATCH + 4 * g + hn) * HID + hc];
    if (tid < 64) vb[(tid >> 4) * 512 + 256 + mem * 16 + (tid & 15)] = 0.f;
    if (tid >= 64) vb[ln * 512 + 256 + lj] = 0.f;
    __syncthreads();

    for (int t = 0; t < SEQ; ++t) {
        float a0 = 0.f, a1 = 0.f, a2 = 0.f, a3 = 0.f;
#pragma unroll
        for (int qq = 0; qq < 8; ++qq) {
            int base = p * 32 + qq * 4;
            float4 v0 = *(const float4*)&vb[base];
            a0 = fmaf(w[qq * 4 + 0], v0.x, a0); a0 = fmaf(w[qq * 4 + 1], v0.y, a0);
            a0 = fmaf(w[qq * 4 + 2], v0.z, a0); a0 = fmaf(w[qq * 4 + 3], v0.w, a0);
            float4 v1 = *(const float4*)&vb[512 + base];
            a1 = fmaf(w[qq * 4 + 0], v1.x, a1); a1 = fmaf(w[qq * 4 + 1], v1.y, a1);
            a1 = fmaf(w[qq * 4 + 2], v1.z, a1); a1 = fmaf(w[qq * 4 + 3], v1.w, a1);
            float4 v2 = *(const float4*)&vb[1024 + base];
            a2 = fmaf(w[qq * 4 + 0], v2.x, a2); a2 = fmaf(w[qq * 4 + 1], v2.y, a2);
            a2 = fmaf(w[qq * 4 + 2], v2.z, a2); a2 = fmaf(w[qq * 4 + 3], v2.w, a2);
            float4 v3 = *(const float4*)&vb[1536 + base];
            a3 = fmaf(w[qq * 4 + 0], v3.x, a3); a3 = fmaf(w[qq * 4 + 1], v3.y, a3);
            a3 = fmaf(w[qq * 4 + 2], v3.z, a3); a3 = fmaf(w[qq * 4 + 3], v3.w, a3);
        }
        if (isHw && t + 1 < SEQ)                       // prefetch h1[t+1]
            hreg = *(const float4*)&hist[((size_t)(t + 1) * BATCH + 4 * g + hn) * HID + hc];
        pb[p * 64 + r]        = a0;
        pb[1032 + p * 64 + r] = a1;
        pb[2064 + p * 64 + r] = a2;
        pb[3096 + p * 64 + r] = a3;
        // FC partial for step t-1 (vb h2-half holds h2[t-1])
        float fval = 0.f;
        if (t > 0 && tid < 512) {
            fval = vb[nf * 512 + 256 + (tid & 255)] * wfc;
            fval += __shfl_xor(fval, 1);
            fval += __shfl_xor(fval, 2);
            fval += __shfl_xor(fval, 4);
            fval += __shfl_xor(fval, 8);
            fval += __shfl_xor(fval, 16);
            fval += __shfl_xor(fval, 32);
            if ((tid & 63) == 0) fcred[tid >> 6] = fval;
        }
        __syncthreads();                               // B1

        const int slot = t & 3;
        const unsigned want = (unsigned)((t + 1) & 7);
        if (tid < 64) {
            int n = tid >> 4, k = tid & 15, b = 4 * g + n;
            float s0 = bias4[0], s1 = bias4[1], s2 = bias4[2], s3 = bias4[3];
#pragma unroll
            for (int q16 = 0; q16 < 16; ++q16) {
                int base = n * 1032 + q16 * 64 + k;
                s0 += pb[base];       s1 += pb[base + 16];
                s2 += pb[base + 32];  s3 += pb[base + 48];
            }
            float iv = sigm(s0), fv = sigm(s1), gv = tanh_f(s2), ov = sigm(s3);
            creg = fv * creg + iv * gv;
            float h = ov * tanh_f(creg);
            vb[n * 512 + 256 + mem * 16 + k] = h;      // own slice
            astore(&ring1[((size_t)slot * BATCH + b) * HID + mem * 16 + k],
                   tagf(h, want));
            // sentinel poll: lanes 0..59
            bool ok = (tid >= 60);
            float* saddr = &ring1[((size_t)slot * BATCH + (4 * g + sn)) * HID + spm * 16 + 15];
            for (;;) {
                if (!ok) ok = tagok(aload(saddr), want);
                if (__all(ok)) break;
                __builtin_amdgcn_s_sleep(1);
            }
            if (tid == 0)
                __hip_atomic_store(&go, t + 1, __ATOMIC_RELAXED,
                                   __HIP_MEMORY_SCOPE_WORKGROUP);
        } else {
            if ((tid == 64 || tid == 65) && t > 0 && (t - 1) < lenb) {
                int cls = tid - 64;
                float s2 = fcred[cls * 4 + 0] + fcred[cls * 4 + 1]
                         + fcred[cls * 4 + 2] + fcred[cls * 4 + 3];
                out[((size_t)(4 * g + nf) * SEQ + (t - 1)) * NCLS + c0 + cls]
                    = (cls ? bfc1 : bfc0) + s2;
            }
            if (isHw && t + 1 < SEQ) *(float4*)&vb[hn * 512 + hc] = hreg;
            while (__hip_atomic_load(&go, __ATOMIC_RELAXED,
                                     __HIP_MEMORY_SCOPE_WORKGROUP) < t + 1)
                __builtin_amdgcn_s_sleep(1);
            float* src = &ring1[((size_t)slot * BATCH + (4 * g + ln)) * HID + lj];
            float hv = aload(src);
            while (!tagok(hv, want)) { __builtin_amdgcn_s_sleep(1); hv = aload(src); }
            vb[ln * 512 + 256 + lj] = hv;
        }
        __syncthreads();                               // B2
    }

    // epilogue: FC for t = SEQ-1 (vb h2-half now holds h2[SEQ-1])
    float fval = 0.f;
    if (tid < 512) {
        fval = vb[nf * 512 + 256 + (tid & 255)] * wfc;
        fval += __shfl_xor(fval, 1);
        fval += __shfl_xor(fval, 2);
        fval += __shfl_xor(fval, 4);
        fval += __shfl_xor(fval, 8);
        fval += __shfl_xor(fval, 16);
        fval += __shfl_xor(fval, 32);
        if ((tid & 63) == 0) fcred[tid >> 6] = fval;
    }
    __syncthreads();
    if (tid < 2 && (SEQ - 1) < lenb) {
        float s2 = fcred[tid * 4 + 0] + fcred[tid * 4 + 1]
                 + fcred[tid * 4 + 2] + fcred[tid * 4 + 3];
        out[((size_t)(4 * g + nf) * SEQ + (SEQ - 1)) * NCLS + c0 + tid]
            = (tid ? bfc1 : bfc0) + s2;
    }
}

// ---------------------------------------------------------------------------
extern "C" void kernel_launch(void* const* d_in, const int* in_sizes, int n_in,
                              void* d_out, int out_size, void* d_ws, size_t ws_size,
                              hipStream_t stream) {
    (void)in_sizes; (void)n_in; (void)out_size;
    const float* x     = (const float*)d_in[0];
    const int*   lens  = (const int*)  d_in[1];
    const float* Wih0  = (const float*)d_in[2];
    const float* Whh0  = (const float*)d_in[3];
    const float* bih0  = (const float*)d_in[4];
    const float* bhh0  = (const float*)d_in[5];
    const float* Wih1  = (const float*)d_in[6];
    const float* Whh1  = (const float*)d_in[7];
    const float* bih1  = (const float*)d_in[8];
    const float* bhh1  = (const float*)d_in[9];
    const float* Wfc   = (const float*)d_in[10];
    const float* bfc   = (const float*)d_in[11];
    float* out = (float*)d_out;
    char*  ws  = (char*)d_ws;

    // ws: ring0(256KB) | ring1(256KB) | hist(128MiB)
    const size_t RING = (size_t)4 * BATCH * HID * 4;   // 256 KB
    float* ring0 = (float*)(ws);
    float* ring1 = (float*)(ws + RING);
    float* hist  = (float*)(ws + 2 * RING);
    const size_t need = 2 * RING + (size_t)SEQ * BATCH * HID * 4;
    if (ws_size < need) return;

    // rings must be zero so no stale/poison dword can alias a valid tag
    hipMemsetAsync(ws, 0, 2 * RING, stream);
    init_out_kernel<<<(BATCH * SEQ * NCLS + 255) / 256, 256, 0, stream>>>(out, bfc);
    lstm_l0_kernel<<<256, 1024, 0, stream>>>(x, Wih0, Whh0, bih0, bhh0, hist, ring0);
    lstm_l1_kernel<<<256, 1024, 0, stream>>>(hist, Wih1, Whh1, bih1, bhh1, Wfc, bfc,
                                             lens, out, ring1);
}